// Round 5
// baseline (348.865 us; speedup 1.0000x reference)
//
#include <hip/hip_runtime.h>

// TemporalBasis: T=512, H=8, BATCH=4, N=4096, B=4; sites S = BATCH*N = 16384.
// z_{t+1} = d*z_t + s_t (per site, per basis k), resp[t][h] = dot(coeffs[h], z_{t+1}).
//
// Fused chunked scan (16 chunks x 32 steps), TWO sites per lane:
//  - spike loads:  float2  (8 B/lane, 512 B/wave)  [was dword]
//  - output stores: float2 (8 B/lane, 512 B/wave)  [was dword]
//  - z0 loads: 2x float4 contiguous (32 B/lane)
// Store width is the single remaining untested write-path variable after
// R1 (burst locality: null) and R2 (nt vs plain store: null).
// Numerics per site identical to R0 baseline.
// (R3/R4 runs died to container-infra failures; source re-audited: all
//  accesses in-bounds & aligned, uniform barriers, single launch.)
#define HH 8
#define BB 4
#define TT 512
#define CHUNKS 16
#define LL (TT / CHUNKS)   // 32
#define SPT 2              // sites per thread
#define SPB (64 * SPT)     // 128 sites per block
#define SPBO 64            // sites per block, fallback kernel

// ---------------- 2 sites/lane, float2 I/O ----------------
__global__ __launch_bounds__(CHUNKS * 64)
void tb_wide(const float* __restrict__ z0,
             const float* __restrict__ spikes,
             const float* __restrict__ taus,
             const float* __restrict__ coeffs,
             const int* __restrict__ dt_p,
             float* __restrict__ out,
             int S) {
    __shared__ float4 lds_P[CHUNKS][64][SPT];   // 32 KB

    const int chunk = threadIdx.x >> 6;          // wave id == chunk id
    const int sl    = threadIdx.x & 63;
    const int site0 = blockIdx.x * SPB + sl * SPT;  // 2 consecutive sites

    const float dt = (float)dt_p[0];
    float d[BB];
#pragma unroll
    for (int k = 0; k < BB; ++k) d[k] = expf(-dt / taus[k]);

    // ---- Phase 1: chunk-local partial sums + spike bitmasks (float2 loads) ----
    const int t0 = chunk * LL;
    float P0[BB] = {0.f, 0.f, 0.f, 0.f};
    float P1[BB] = {0.f, 0.f, 0.f, 0.f};
    unsigned m0 = 0u, m1 = 0u;
    const float2* __restrict__ sp =
        (const float2*)(spikes + (size_t)t0 * S + site0);
    const size_t sstride = (size_t)S / 2;        // float2 units
#pragma unroll
    for (int i = 0; i < LL; ++i) {
        const float2 s2 = sp[(size_t)i * sstride];
        m0 |= (s2.x != 0.f ? 1u : 0u) << i;
        m1 |= (s2.y != 0.f ? 1u : 0u) << i;
#pragma unroll
        for (int k = 0; k < BB; ++k) {
            P0[k] = d[k] * P0[k] + s2.x;
            P1[k] = d[k] * P1[k] + s2.y;
        }
    }
    lds_P[chunk][sl][0] = make_float4(P0[0], P0[1], P0[2], P0[3]);
    lds_P[chunk][sl][1] = make_float4(P1[0], P1[1], P1[2], P1[3]);
    __syncthreads();

    // d^L via 5 squarings (L = 32)
    float dL[BB];
#pragma unroll
    for (int k = 0; k < BB; ++k) {
        float x = d[k];
        x = x * x; x = x * x; x = x * x; x = x * x; x = x * x;
        dL[k] = x;
    }

    // ---- Phase 2: combine prior chunks -> spike-driven state at t0 ----
    float A0[BB] = {0.f, 0.f, 0.f, 0.f};
    float A1[BB] = {0.f, 0.f, 0.f, 0.f};
    for (int e = 0; e < chunk; ++e) {
        const float4 p0 = lds_P[e][sl][0];
        const float4 p1 = lds_P[e][sl][1];
        A0[0] = dL[0] * A0[0] + p0.x;  A1[0] = dL[0] * A1[0] + p1.x;
        A0[1] = dL[1] * A0[1] + p0.y;  A1[1] = dL[1] * A1[1] + p1.y;
        A0[2] = dL[2] * A0[2] + p0.z;  A1[2] = dL[2] * A1[2] + p1.z;
        A0[3] = dL[3] * A0[3] + p0.w;  A1[3] = dL[3] * A1[3] + p1.w;
    }

    // d^(t0) = (d^L)^chunk
    float dt0[BB] = {1.f, 1.f, 1.f, 1.f};
    for (int e = 0; e < chunk; ++e) {
#pragma unroll
        for (int k = 0; k < BB; ++k) dt0[k] *= dL[k];
    }

    // init z[h][site][k] = d^(t0) * z0[h][site][k] + A[site][k]
    float z[HH][SPT][BB];
#pragma unroll
    for (int h = 0; h < HH; ++h) {
        const float4 zv0 = ((const float4*)z0)[(size_t)h * S + site0];
        const float4 zv1 = ((const float4*)z0)[(size_t)h * S + site0 + 1];
        z[h][0][0] = dt0[0] * zv0.x + A0[0];
        z[h][0][1] = dt0[1] * zv0.y + A0[1];
        z[h][0][2] = dt0[2] * zv0.z + A0[2];
        z[h][0][3] = dt0[3] * zv0.w + A0[3];
        z[h][1][0] = dt0[0] * zv1.x + A1[0];
        z[h][1][1] = dt0[1] * zv1.y + A1[1];
        z[h][1][2] = dt0[2] * zv1.z + A1[2];
        z[h][1][3] = dt0[3] * zv1.w + A1[3];
    }

    // mixing coefficients (wave-uniform -> SGPRs)
    float c[HH][BB];
#pragma unroll
    for (int h = 0; h < HH; ++h)
#pragma unroll
        for (int k = 0; k < BB; ++k) c[h][k] = coeffs[h * BB + k];

    // ---- replay loop: stores only, float2 per (step, head) ----
    float2* __restrict__ op =
        (float2*)(out + (size_t)t0 * HH * S + site0);
    const size_t ostride = (size_t)S / 2;        // float2 units
#pragma unroll 2
    for (int i = 0; i < LL; ++i) {
        const float s0 = (m0 & (1u << i)) ? 1.0f : 0.0f;
        const float s1 = (m1 & (1u << i)) ? 1.0f : 0.0f;
#pragma unroll
        for (int h = 0; h < HH; ++h) {
#pragma unroll
            for (int k = 0; k < BB; ++k) {
                z[h][0][k] = d[k] * z[h][0][k] + s0;
                z[h][1][k] = d[k] * z[h][1][k] + s1;
            }
            const float r0 = z[h][0][0] * c[h][0] + z[h][0][1] * c[h][1] +
                             z[h][0][2] * c[h][2] + z[h][0][3] * c[h][3];
            const float r1 = z[h][1][0] * c[h][0] + z[h][1][1] * c[h][1] +
                             z[h][1][2] * c[h][2] + z[h][1][3] * c[h][3];
            op[(size_t)(i * HH + h) * ostride] = make_float2(r0, r1);
        }
    }
}

// ---------------- Fallback: R0/R2 fused kernel (1 site/lane) ----------------
__global__ __launch_bounds__(CHUNKS * SPBO)
void temporal_basis_kernel(const float* __restrict__ z0,
                           const float* __restrict__ spikes,
                           const float* __restrict__ taus,
                           const float* __restrict__ coeffs,
                           const int* __restrict__ dt_p,
                           float* __restrict__ out,
                           int S) {
    __shared__ float4 lds_P[CHUNKS][SPBO];

    const int chunk = threadIdx.x >> 6;
    const int sl    = threadIdx.x & 63;
    const int site  = blockIdx.x * SPBO + sl;

    const float dt = (float)dt_p[0];
    float d[BB];
#pragma unroll
    for (int k = 0; k < BB; ++k) d[k] = expf(-dt / taus[k]);

    const int t0 = chunk * LL;
    float P[BB] = {0.f, 0.f, 0.f, 0.f};
    unsigned mask = 0u;
    const float* __restrict__ sp = spikes + (size_t)t0 * S + site;
#pragma unroll
    for (int i = 0; i < LL; ++i) {
        const float s = sp[(size_t)i * S];
        mask |= (s != 0.f ? 1u : 0u) << i;
#pragma unroll
        for (int k = 0; k < BB; ++k) P[k] = d[k] * P[k] + s;
    }
    lds_P[chunk][sl] = make_float4(P[0], P[1], P[2], P[3]);
    __syncthreads();

    float dL[BB];
#pragma unroll
    for (int k = 0; k < BB; ++k) {
        float x = d[k];
        x = x * x; x = x * x; x = x * x; x = x * x; x = x * x;
        dL[k] = x;
    }

    float A[BB] = {0.f, 0.f, 0.f, 0.f};
    for (int e = 0; e < chunk; ++e) {
        const float4 p = lds_P[e][sl];
        A[0] = dL[0] * A[0] + p.x;
        A[1] = dL[1] * A[1] + p.y;
        A[2] = dL[2] * A[2] + p.z;
        A[3] = dL[3] * A[3] + p.w;
    }

    float dt0[BB] = {1.f, 1.f, 1.f, 1.f};
    for (int e = 0; e < chunk; ++e) {
#pragma unroll
        for (int k = 0; k < BB; ++k) dt0[k] *= dL[k];
    }

    float z[HH][BB];
#pragma unroll
    for (int h = 0; h < HH; ++h) {
        const float4 zv = ((const float4*)z0)[(size_t)h * S + site];
        z[h][0] = dt0[0] * zv.x + A[0];
        z[h][1] = dt0[1] * zv.y + A[1];
        z[h][2] = dt0[2] * zv.z + A[2];
        z[h][3] = dt0[3] * zv.w + A[3];
    }

    float c[HH][BB];
#pragma unroll
    for (int h = 0; h < HH; ++h)
#pragma unroll
        for (int k = 0; k < BB; ++k) c[h][k] = coeffs[h * BB + k];

    float* __restrict__ op = out + (size_t)t0 * HH * S + site;
#pragma unroll 4
    for (int i = 0; i < LL; ++i) {
        const float s = (mask & (1u << i)) ? 1.0f : 0.0f;
#pragma unroll
        for (int h = 0; h < HH; ++h) {
#pragma unroll
            for (int k = 0; k < BB; ++k) z[h][k] = d[k] * z[h][k] + s;
            const float r = z[h][0] * c[h][0] + z[h][1] * c[h][1] +
                            z[h][2] * c[h][2] + z[h][3] * c[h][3];
            op[(size_t)(i * HH + h) * S] = r;
        }
    }
}

extern "C" void kernel_launch(void* const* d_in, const int* in_sizes, int n_in,
                              void* d_out, int out_size, void* d_ws, size_t ws_size,
                              hipStream_t stream) {
    const float* z0     = (const float*)d_in[0];
    const float* spikes = (const float*)d_in[1];
    const float* taus   = (const float*)d_in[2];
    const float* coeffs = (const float*)d_in[3];
    const int*   dt_p   = (const int*)d_in[4];
    float* out = (float*)d_out;

    const int S = in_sizes[1] / TT;   // 16384 sites

    if ((S % SPB) == 0) {
        tb_wide<<<S / SPB, CHUNKS * 64, 0, stream>>>(
            z0, spikes, taus, coeffs, dt_p, out, S);
    } else {
        temporal_basis_kernel<<<S / SPBO, CHUNKS * SPBO, 0, stream>>>(
            z0, spikes, taus, coeffs, dt_p, out, S);
    }
}